// Round 20
// baseline (155.092 us; speedup 1.0000x reference)
//
#include <hip/hip_runtime.h>
#include <stdint.h>

// minerva2: echo = (F̂ Ê^T)^3 @ V, intensity = rowsum((F̂ Ê^T)^3)
// R20: 1024-thread blocks, 16 waves = 4wr x 4wd, wave = 32q x 16d.
// Holds LDS-reads AND staging at R18 parity while reaching 4 waves/SIMD
// (1 block/CU). qA[2][8]=64 regs. PV uses the y=0 cvtpk/swap2 trick for
// 16-d A-frags (k>=16 lanes zero). R12-proven sub-slab swizzle. NSLOT=16
// (wd pairs merged in LDS; pair id in slot).

typedef unsigned short u16;
typedef __bf16 bf16x8 __attribute__((ext_vector_type(8)));
typedef float f32x4 __attribute__((ext_vector_type(4)));
typedef unsigned short u16x4 __attribute__((ext_vector_type(4)));

#define NQ 8192
#define ND 16384
#define NH 256
#define NC 28
#define DCHUNK 2048
#define NDT 32       // 64-row D-tiles per chunk
#define NSLOT 16     // partial slots = 8 dch x 2 wd-pairs

__device__ __forceinline__ u16 f2bf(float f) {
  unsigned u = __builtin_bit_cast(unsigned, f);
  u += 0x7fffu + ((u >> 16) & 1u);   // RNE
  return (u16)(u >> 16);
}

__device__ __forceinline__ unsigned cvtpk(float lo, float hi) {
  unsigned r;
  asm("v_cvt_pk_bf16_f32 %0, %1, %2" : "=v"(r) : "v"(lo), "v"(hi));
  return r;  // low16 = bf16(lo), high16 = bf16(hi)  (RNE)
}

// After: x = [x.r0, x.r2, y.r0, y.r2] (by 16-lane row), y = [x.r1, x.r3, y.r1, y.r3]
__device__ __forceinline__ void swap2(unsigned& x, unsigned& y) {
  asm("v_permlane32_swap_b32 %0, %1" : "+v"(x), "+v"(y));  // x.r23 <-> y.r01
  asm("v_permlane16_swap_b32 %0, %1" : "+v"(x), "+v"(y));  // x.r1<->y.r0, x.r3<->y.r2
}

__device__ __forceinline__ void gload16(const void* g, void* l) {
  // async global->LDS, 16B/lane; LDS dest = wave-uniform base + lane*16
  __builtin_amdgcn_global_load_lds(
      (__attribute__((address_space(1))) void*)g,
      (__attribute__((address_space(3))) void*)l, 16, 0, 0);
}

// ---- prep: rows 0..24575 = L2-normalize (feat->qn, exf->kn); then Vt ------
__global__ __launch_bounds__(256) void prep_kernel(
    const float* __restrict__ feat, const float* __restrict__ exf,
    const float* __restrict__ V, u16* __restrict__ qn, u16* __restrict__ kn,
    u16* __restrict__ Vt) {
  if (blockIdx.x < 6144) {
    const int wid = threadIdx.x >> 6, lane = threadIdx.x & 63;
    const int row = blockIdx.x * 4 + wid;
    const float* in = (row < NQ) ? feat + (size_t)row * NH
                                 : exf + (size_t)(row - NQ) * NH;
    u16* out = (row < NQ) ? qn + (size_t)row * NH : kn + (size_t)(row - NQ) * NH;
    float4 v = ((const float4*)in)[lane];
    float ss = v.x * v.x + v.y * v.y + v.z * v.z + v.w * v.w;
#pragma unroll
    for (int m = 1; m <= 32; m <<= 1) ss += __shfl_xor(ss, m, 64);
    const float sc = 1.0f / fmaxf(sqrtf(ss), 1e-12f);  // matches F.normalize eps
    u16x4 o;
    o.x = f2bf(v.x * sc); o.y = f2bf(v.y * sc);
    o.z = f2bf(v.z * sc); o.w = f2bf(v.w * sc);
    *(u16x4*)(out + lane * 4) = o;
  } else {
    const int d = (blockIdx.x - 6144) * 256 + threadIdx.x;  // 16384
#pragma unroll
    for (int c = 0; c < NC; ++c) Vt[(size_t)c * ND + d] = f2bf(V[(size_t)d * NC + c]);
    Vt[(size_t)28 * ND + d] = 0x3F80;  // bf16 1.0 -> echo col 28 == intensity
    Vt[(size_t)29 * ND + d] = 0;
    Vt[(size_t)30 * ND + d] = 0;
    Vt[(size_t)31 * ND + d] = 0;
  }
}

// ---------------- fused main kernel ----------------------------------------
// grid 512 x 1024thr: dch = bid&7 (2MB K-chunk per XCD), ntile = bid>>3 (128q).
// 16 waves = 4 wr x 4 wd: wave owns q-rows [ntile*128+wr*32,+32) x
// d-rows [wd*16,+16) of each 64-row D-tile. 1 block/CU (4 waves/SIMD).
// LDS 32KB = 2 bufs [4 k2][64 d][64B]; R12-proven sub-slab swizzle.
__global__ __launch_bounds__(1024, 4) void fused_kernel(
    const u16* __restrict__ Qn, const u16* __restrict__ Kn,
    const u16* __restrict__ Vt, float* __restrict__ ep) {
  __shared__ alignas(16) char smem[32768];
  const int tid = threadIdx.x;
  const int wid = tid >> 6;
  const int lane = tid & 63;
  const int l16 = lane & 15;
  const int lg = lane >> 4;
  const int wr = wid >> 2;
  const int wd = wid & 3;
  const int dch = blockIdx.x & 7;
  const int ntile = blockIdx.x >> 3;
  const int rowbase = ntile * 128 + wr * 32;

  // ---- Q fragments, 32 rows x all H, in registers (MFMA B-operand) ----
  bf16x8 qA[2][8];
#pragma unroll
  for (int mb = 0; mb < 2; ++mb)
#pragma unroll
    for (int ks = 0; ks < 8; ++ks)
      qA[mb][ks] = *(const bf16x8*)(Qn + (size_t)(rowbase + mb * 16 + l16) * NH +
                                    ks * 32 + lg * 8);

  f32x4 eacc[2][2];
#pragma unroll
  for (int mb = 0; mb < 2; ++mb) {
    eacc[mb][0] = f32x4{0.f, 0.f, 0.f, 0.f};
    eacc[mb][1] = f32x4{0.f, 0.f, 0.f, 0.f};
  }
  f32x4 sacc[2];

  const u16* kc = Kn + (size_t)dch * DCHUNK * NH;
  // staging (1024 thr, 1 gload16 each): LDS dest = tid*16 within buf ->
  // k2 = tid>>8, d = (tid>>2)&63, stored chunk = tid&3,
  // logical chunk = (tid&3) ^ ((d>>1)&3) = (tid&3) ^ ((tid>>3)&3)
  const int srow = (tid >> 2) & 63;
  const u16* kb = kc + (size_t)srow * NH + ((tid & 3) ^ ((tid >> 3) & 3)) * 8 +
                  (tid >> 8) * 32;

  // stage one [64d][128k] half-tile -> buf as 4 sub-slabs [64d][64B]
  auto stage = [&](int buf, const u16* src0) {
    gload16(src0, smem + buf * 16384 + wid * 1024);
  };

  const int rsw = (l16 >> 1) & 3;  // (row>>1)&3 for row = wd*16 + l16 (16wd==0 mod 8)

  // compute one staged half h (buf): wave reads only its wd 16-d slice
  auto compute = [&](int buf, int h) {
    const char* kbuf = smem + buf * 16384;
#pragma unroll
    for (int k2 = 0; k2 < 4; ++k2) {
      const bf16x8 B = *(const bf16x8*)(kbuf + k2 * 4096 + (wd * 16 + l16) * 64 +
                                        ((lg ^ rsw) << 4));
      __builtin_amdgcn_s_setprio(1);
#pragma unroll
      for (int mb = 0; mb < 2; ++mb)
        sacc[mb] = __builtin_amdgcn_mfma_f32_16x16x32_bf16(
            B, qA[mb][h * 4 + k2], sacc[mb], 0, 0, 0);
      __builtin_amdgcn_s_setprio(0);
    }
  };

  // prologue: tile 0 half 0 -> buf 0
  stage(0, kb);
  __syncthreads();

  for (int t = 0; t < NDT; ++t) {
    const size_t toff = (size_t)t * 64 * NH;
    const int dbase = dch * DCHUNK + t * 64 + wd * 16;

    sacc[0] = f32x4{0.f, 0.f, 0.f, 0.f};
    sacc[1] = f32x4{0.f, 0.f, 0.f, 0.f};

    // s0: stage half1 -> buf1, compute half0 (buf0)
    stage(1, kb + toff + 128);
    compute(0, 0);
    __syncthreads();  // BAR1: buf1 staged; buf0 reads done (before next stage(0))

    // s1: stage next tile half0 -> buf0, compute half1 (buf1)
    if (t < NDT - 1) stage(0, kb + toff + 64 * NH);
    compute(1, 1);

    // vB: element i at lane-group lg holds V^T[c][dbase + lg*8 + i] for lg<2
    // (lg>=2 lanes multiply zero A; reuse lg&1 values to stay in-bounds)
    bf16x8 vB[2];
#pragma unroll
    for (int cn = 0; cn < 2; ++cn)
      vB[cn] = *(const bf16x8*)(Vt + (size_t)(cn * 16 + l16) * ND + dbase +
                                (lg & 1) * 8);

    // ---- cube (fp32) -> bf16 pack -> y=0 swap2 transpose -> PV MFMA ----
    // sacc[mb]: q = l16, d = wd*16 + lg*4 + r (16 d per wave).
#pragma unroll
    for (int mb = 0; mb < 2; ++mb) {
      f32x4 sx = sacc[mb];
      f32x4 cx = sx * sx * sx;
      unsigned x0 = cvtpk(cx[0], cx[1]);  // d = 4lg+0,1
      unsigned x1 = cvtpk(cx[2], cx[3]);  // d = 4lg+2,3
      unsigned y0 = 0, y1 = 0;
      swap2(x0, y0);  // x0 -> a0 (k 8g+0,1 | rows>=2: 0), y0 -> a2 (k 8g+4,5)
      swap2(x1, y1);  // x1 -> a1 (k 8g+2,3), y1 -> a3 (k 8g+6,7)
      const int4 ai = {(int)x0, (int)x1, (int)y0, (int)y1};
      const bf16x8 aA = __builtin_bit_cast(bf16x8, ai);
#pragma unroll
      for (int cn = 0; cn < 2; ++cn)
        eacc[mb][cn] = __builtin_amdgcn_mfma_f32_16x16x32_bf16(
            aA, vB[cn], eacc[mb][cn], 0, 0, 0);
    }

    __syncthreads();  // BAR2 (after PV): buf1 reads done before next stage(1);
                      // stage(0) drain hidden under compute(1,1)+PV
  }

  // ---- epilogue: merge wd pairs (1->0, 3->2) via LDS; slot = dch*2+pair ----
  float* eml = (float*)smem;  // [pair(2)][wr(4)][64 lanes][16 f32] = 32KB
  if (wd & 1) {
    float* dst = eml + (((wd >> 1) * 4 + wr) * 64 + lane) * 16;
#pragma unroll
    for (int mb = 0; mb < 2; ++mb)
#pragma unroll
      for (int cn = 0; cn < 2; ++cn)
        *(f32x4*)(dst + (mb * 2 + cn) * 4) = eacc[mb][cn];
  }
  __syncthreads();
  if (!(wd & 1)) {
    const float* src = eml + (((wd >> 1) * 4 + wr) * 64 + lane) * 16;
    const int slot = dch * 2 + (wd >> 1);
#pragma unroll
    for (int mb = 0; mb < 2; ++mb)
#pragma unroll
      for (int cn = 0; cn < 2; ++cn) {
        const f32x4 m = eacc[mb][cn] + *(const f32x4*)(src + (mb * 2 + cn) * 4);
#pragma unroll
        for (int r = 0; r < 4; ++r) {
          const int row = rowbase + mb * 16 + lg * 4 + r;
          ep[((size_t)slot * NQ + row) * 32 + cn * 16 + l16] = m[r];
        }
      }
  }
}

// ---------------- reduce 16 partial slots -> d_out -------------------------
__global__ __launch_bounds__(256) void reduce_kernel(const float* __restrict__ ep,
                                                     float* __restrict__ out) {
  const int g = blockIdx.x * 256 + threadIdx.x;  // 8192*32
  const int q = g >> 5, c = g & 31;
  if (c < NC) {
    float s = 0.f;
#pragma unroll
    for (int k = 0; k < NSLOT; ++k) s += ep[((size_t)k * NQ + q) * 32 + c];
    out[(size_t)q * NC + c] = s;
  } else if (c == NC) {  // ones-column == intensity
    float s = 0.f;
#pragma unroll
    for (int k = 0; k < NSLOT; ++k) s += ep[((size_t)k * NQ + q) * 32 + NC];
    out[(size_t)NQ * NC + q] = s;
  }
}

extern "C" void kernel_launch(void* const* d_in, const int* in_sizes, int n_in,
                              void* d_out, int out_size, void* d_ws, size_t ws_size,
                              hipStream_t stream) {
  const float* feat = (const float*)d_in[0];  // [8192][256]
  const float* exf  = (const float*)d_in[1];  // [16384][256]
  const float* exc  = (const float*)d_in[2];  // [16384][28]
  float* out = (float*)d_out;
  char* ws = (char*)d_ws;
  // ws layout: qn 4MB | kn 8MB | vt 1MB | ep 16MB  (~29MB)
  u16* qn = (u16*)ws;
  u16* kn = (u16*)(ws + 4194304);
  u16* vt = (u16*)(ws + 12582912);
  float* ep = (float*)(ws + 13631488);

  prep_kernel<<<dim3(6208), dim3(256), 0, stream>>>(feat, exf, exc, qn, kn, vt);
  fused_kernel<<<dim3(512), dim3(1024), 0, stream>>>(qn, kn, vt, ep);
  reduce_kernel<<<dim3(NQ * 32 / 256), dim3(256), 0, stream>>>(ep, out);
}

// Round 21
// 83.805 us; speedup vs baseline: 1.8506x; 1.8506x over previous
//
#include <hip/hip_runtime.h>
#include <stdint.h>

// minerva2: echo = (F̂ Ê^T)^3 @ V, intensity = rowsum((F̂ Ê^T)^3)
// R21 = R18 (best: 2x2 wave grid 64qx32d, qA[4][8] resident, R12-proven
// swizzle, NSLOT=8) + BAR2 moved AFTER PV: the stage(0) vmcnt-drain implied
// by __syncthreads now overlaps PV's VALU+MFMA work instead of stalling.

typedef unsigned short u16;
typedef __bf16 bf16x8 __attribute__((ext_vector_type(8)));
typedef float f32x4 __attribute__((ext_vector_type(4)));
typedef unsigned short u16x4 __attribute__((ext_vector_type(4)));

#define NQ 8192
#define ND 16384
#define NH 256
#define NC 28
#define DCHUNK 2048
#define NDT 32       // 64-row D-tiles per chunk
#define NSLOT 8      // partial slots = 8 D-chunks (one per XCD; wd merged)

__device__ __forceinline__ u16 f2bf(float f) {
  unsigned u = __builtin_bit_cast(unsigned, f);
  u += 0x7fffu + ((u >> 16) & 1u);   // RNE
  return (u16)(u >> 16);
}

__device__ __forceinline__ unsigned cvtpk(float lo, float hi) {
  unsigned r;
  asm("v_cvt_pk_bf16_f32 %0, %1, %2" : "=v"(r) : "v"(lo), "v"(hi));
  return r;  // low16 = bf16(lo), high16 = bf16(hi)  (RNE)
}

// After: x = [x.r0, x.r2, y.r0, y.r2] (by 16-lane row), y = [x.r1, x.r3, y.r1, y.r3]
__device__ __forceinline__ void swap2(unsigned& x, unsigned& y) {
  asm("v_permlane32_swap_b32 %0, %1" : "+v"(x), "+v"(y));  // x.r23 <-> y.r01
  asm("v_permlane16_swap_b32 %0, %1" : "+v"(x), "+v"(y));  // x.r1<->y.r0, x.r3<->y.r2
}

__device__ __forceinline__ void gload16(const void* g, void* l) {
  // async global->LDS, 16B/lane; LDS dest = wave-uniform base + lane*16
  __builtin_amdgcn_global_load_lds(
      (__attribute__((address_space(1))) void*)g,
      (__attribute__((address_space(3))) void*)l, 16, 0, 0);
}

// ---- prep: rows 0..24575 = L2-normalize (feat->qn, exf->kn); then Vt ------
__global__ __launch_bounds__(256) void prep_kernel(
    const float* __restrict__ feat, const float* __restrict__ exf,
    const float* __restrict__ V, u16* __restrict__ qn, u16* __restrict__ kn,
    u16* __restrict__ Vt) {
  if (blockIdx.x < 6144) {
    const int wid = threadIdx.x >> 6, lane = threadIdx.x & 63;
    const int row = blockIdx.x * 4 + wid;
    const float* in = (row < NQ) ? feat + (size_t)row * NH
                                 : exf + (size_t)(row - NQ) * NH;
    u16* out = (row < NQ) ? qn + (size_t)row * NH : kn + (size_t)(row - NQ) * NH;
    float4 v = ((const float4*)in)[lane];
    float ss = v.x * v.x + v.y * v.y + v.z * v.z + v.w * v.w;
#pragma unroll
    for (int m = 1; m <= 32; m <<= 1) ss += __shfl_xor(ss, m, 64);
    const float sc = 1.0f / fmaxf(sqrtf(ss), 1e-12f);  // matches F.normalize eps
    u16x4 o;
    o.x = f2bf(v.x * sc); o.y = f2bf(v.y * sc);
    o.z = f2bf(v.z * sc); o.w = f2bf(v.w * sc);
    *(u16x4*)(out + lane * 4) = o;
  } else {
    const int d = (blockIdx.x - 6144) * 256 + threadIdx.x;  // 16384
#pragma unroll
    for (int c = 0; c < NC; ++c) Vt[(size_t)c * ND + d] = f2bf(V[(size_t)d * NC + c]);
    Vt[(size_t)28 * ND + d] = 0x3F80;  // bf16 1.0 -> echo col 28 == intensity
    Vt[(size_t)29 * ND + d] = 0;
    Vt[(size_t)30 * ND + d] = 0;
    Vt[(size_t)31 * ND + d] = 0;
  }
}

// ---------------- fused main kernel ----------------------------------------
// grid 512: dch = bid&7 (one 2MB K-chunk per XCD, L2-resident), ntile = bid>>3.
// 4 waves, 2x2: wave (wr, wd) owns q-rows [ntile*128+wr*64, +64) x
// d-rows [wd*32, +32) of each 64-row D-tile.
// Q (all H) in registers (128 VGPR). LDS 32KB = 2 bufs [4 k2][64 d][64B].
// Sub-slab swizzle (R12-proven): stored chunk p at row R = logical p^((R>>1)&3).
__global__ __launch_bounds__(256, 2) void fused_kernel(
    const u16* __restrict__ Qn, const u16* __restrict__ Kn,
    const u16* __restrict__ Vt, float* __restrict__ ep) {
  __shared__ alignas(16) char smem[32768];
  const int tid = threadIdx.x;
  const int wid = tid >> 6;
  const int lane = tid & 63;
  const int l16 = lane & 15;
  const int lg = lane >> 4;
  const int wr = wid >> 1;
  const int wd = wid & 1;
  const int dch = blockIdx.x & 7;
  const int ntile = blockIdx.x >> 3;
  const int rowbase = ntile * 128 + wr * 64;

  // ---- Q fragments, 64 rows x all H, in registers (MFMA B-operand) ----
  bf16x8 qA[4][8];
#pragma unroll
  for (int mb = 0; mb < 4; ++mb)
#pragma unroll
    for (int ks = 0; ks < 8; ++ks)
      qA[mb][ks] = *(const bf16x8*)(Qn + (size_t)(rowbase + mb * 16 + l16) * NH +
                                    ks * 32 + lg * 8);

  f32x4 eacc[4][2];
#pragma unroll
  for (int mb = 0; mb < 4; ++mb) {
    eacc[mb][0] = f32x4{0.f, 0.f, 0.f, 0.f};
    eacc[mb][1] = f32x4{0.f, 0.f, 0.f, 0.f};
  }
  f32x4 sacc[4][2];

  const u16* kc = Kn + (size_t)dch * DCHUNK * NH;
  // staging decomposition (unchanged): d = (tid>>6)*16 + ((tid>>2)&15),
  // stored chunk = tid&3, logical chunk = (tid&3) ^ ((tid>>3)&3)
  const int srow = (tid >> 6) * 16 + ((tid >> 2) & 15);
  const u16* kb = kc + (size_t)srow * NH + ((tid & 3) ^ ((tid >> 3) & 3)) * 8;

  // stage one [64d][128k] half-tile -> buf as 4 sub-slabs [64d][64B]
  auto stage = [&](int buf, const u16* src0) {
#pragma unroll
    for (int r = 0; r < 4; ++r)
      gload16(src0 + r * 32,
              smem + buf * 16384 + r * 4096 + wid * 1024);
  };

  const int rsw = (l16 >> 1) & 3;  // (row>>1)&3 for row = wd*32 + nb*16 + l16

  // compute one staged half h (buf): wave reads only its wd 32-d slice
  auto compute = [&](int buf, int h) {
    const char* kbuf = smem + buf * 16384;
#pragma unroll
    for (int k2 = 0; k2 < 4; ++k2) {
      bf16x8 B[2];
#pragma unroll
      for (int nb = 0; nb < 2; ++nb)
        B[nb] = *(const bf16x8*)(kbuf + k2 * 4096 + (wd * 32 + nb * 16 + l16) * 64 +
                                 ((lg ^ rsw) << 4));
      __builtin_amdgcn_s_setprio(1);
#pragma unroll
      for (int mb = 0; mb < 4; ++mb)
#pragma unroll
        for (int nb = 0; nb < 2; ++nb)
          sacc[mb][nb] = __builtin_amdgcn_mfma_f32_16x16x32_bf16(
              B[nb], qA[mb][h * 4 + k2], sacc[mb][nb], 0, 0, 0);
      __builtin_amdgcn_s_setprio(0);
    }
  };

  // prologue: tile 0 half 0 -> buf 0
  stage(0, kb);
  __syncthreads();

  for (int t = 0; t < NDT; ++t) {
    const size_t toff = (size_t)t * 64 * NH;
    const int dbase = dch * DCHUNK + t * 64 + wd * 32;

#pragma unroll
    for (int mb = 0; mb < 4; ++mb) {
      sacc[mb][0] = f32x4{0.f, 0.f, 0.f, 0.f};
      sacc[mb][1] = f32x4{0.f, 0.f, 0.f, 0.f};
    }

    // s0: stage half1 -> buf1, compute half0 (buf0)
    stage(1, kb + toff + 128);
    compute(0, 0);
    __syncthreads();  // BAR1: buf1 staged; buf0 reads done (before next stage(0))

    // vB loads here: live range = through PV only; drain under compute(1,1)
    bf16x8 vB[2];
#pragma unroll
    for (int cn = 0; cn < 2; ++cn)
      vB[cn] = *(const bf16x8*)(Vt + (size_t)(cn * 16 + l16) * ND + dbase + lg * 8);

    // s1: stage next tile half0 -> buf0, compute half1 (buf1)
    if (t < NDT - 1) stage(0, kb + toff + 64 * NH);
    compute(1, 1);

    // ---- cube (fp32) -> bf16 pack -> permlane transpose -> PV MFMA ----
    // sacc[mb][nb]: q = l16, d = wd*32 + nb*16 + lg*4 + r.  (LDS-free)
#pragma unroll
    for (int mb = 0; mb < 4; ++mb) {
      f32x4 sx = sacc[mb][0];
      f32x4 sy = sacc[mb][1];
      f32x4 cx = sx * sx * sx;
      f32x4 cy = sy * sy * sy;
      unsigned x0 = cvtpk(cx[0], cx[1]);  // d = 4lg+0,1   (nb = 0)
      unsigned x1 = cvtpk(cx[2], cx[3]);  // d = 4lg+2,3
      unsigned y0 = cvtpk(cy[0], cy[1]);  // same, nb = 1
      unsigned y1 = cvtpk(cy[2], cy[3]);
      swap2(x0, y0);  // x0 -> a0 (k 8g+0,1), y0 -> a2 (k 8g+4,5)
      swap2(x1, y1);  // x1 -> a1 (k 8g+2,3), y1 -> a3 (k 8g+6,7)
      const int4 ai = {(int)x0, (int)x1, (int)y0, (int)y1};
      const bf16x8 aA = __builtin_bit_cast(bf16x8, ai);
#pragma unroll
      for (int cn = 0; cn < 2; ++cn)
        eacc[mb][cn] = __builtin_amdgcn_mfma_f32_16x16x32_bf16(
            aA, vB[cn], eacc[mb][cn], 0, 0, 0);
    }

    __syncthreads();  // BAR2 (after PV): buf1 reads done before next stage(1);
                      // stage(0) drain hidden under compute(1,1)+PV
  }

  // ---- epilogue: merge wd=1 into wd=0 via LDS (bufs dead), slot = dch ----
  float* eml = (float*)smem;  // [2 wr][64 lanes][36 dwords] = 18KB
  if (wd == 1) {
    float* dst = eml + (wr * 64 + lane) * 36;
#pragma unroll
    for (int mb = 0; mb < 4; ++mb)
#pragma unroll
      for (int cn = 0; cn < 2; ++cn)
        *(f32x4*)(dst + (mb * 2 + cn) * 4) = eacc[mb][cn];
  }
  __syncthreads();
  if (wd == 0) {
    const float* src = eml + (wr * 64 + lane) * 36;
#pragma unroll
    for (int mb = 0; mb < 4; ++mb)
#pragma unroll
      for (int cn = 0; cn < 2; ++cn) {
        const f32x4 m = eacc[mb][cn] + *(const f32x4*)(src + (mb * 2 + cn) * 4);
#pragma unroll
        for (int r = 0; r < 4; ++r) {
          const int row = rowbase + mb * 16 + lg * 4 + r;
          ep[((size_t)dch * NQ + row) * 32 + cn * 16 + l16] = m[r];
        }
      }
  }
}

// ---------------- reduce 8 partial slots -> d_out --------------------------
__global__ __launch_bounds__(256) void reduce_kernel(const float* __restrict__ ep,
                                                     float* __restrict__ out) {
  const int g = blockIdx.x * 256 + threadIdx.x;  // 8192*32
  const int q = g >> 5, c = g & 31;
  if (c < NC) {
    float s = 0.f;
#pragma unroll
    for (int k = 0; k < NSLOT; ++k) s += ep[((size_t)k * NQ + q) * 32 + c];
    out[(size_t)q * NC + c] = s;
  } else if (c == NC) {  // ones-column == intensity
    float s = 0.f;
#pragma unroll
    for (int k = 0; k < NSLOT; ++k) s += ep[((size_t)k * NQ + q) * 32 + NC];
    out[(size_t)NQ * NC + q] = s;
  }
}

extern "C" void kernel_launch(void* const* d_in, const int* in_sizes, int n_in,
                              void* d_out, int out_size, void* d_ws, size_t ws_size,
                              hipStream_t stream) {
  const float* feat = (const float*)d_in[0];  // [8192][256]
  const float* exf  = (const float*)d_in[1];  // [16384][256]
  const float* exc  = (const float*)d_in[2];  // [16384][28]
  float* out = (float*)d_out;
  char* ws = (char*)d_ws;
  // ws layout: qn 4MB | kn 8MB | vt 1MB | ep 8MB  (~21MB)
  u16* qn = (u16*)ws;
  u16* kn = (u16*)(ws + 4194304);
  u16* vt = (u16*)(ws + 12582912);
  float* ep = (float*)(ws + 13631488);

  prep_kernel<<<dim3(6208), dim3(256), 0, stream>>>(feat, exf, exc, qn, kn, vt);
  fused_kernel<<<dim3(512), dim3(256), 0, stream>>>(qn, kn, vt, ep);
  reduce_kernel<<<dim3(NQ * 32 / 256), dim3(256), 0, stream>>>(ep, out);
}

// Round 22
// 82.040 us; speedup vs baseline: 1.8904x; 1.0215x over previous
//
#include <hip/hip_runtime.h>
#include <stdint.h>

// minerva2: echo = (F̂ Ê^T)^3 @ V, intensity = rowsum((F̂ Ê^T)^3)
// R22 = R18 with FULL-TILE double buffering: LDS 64KB = 2 bufs of
// [8 k2][64 d][64B] (32KB each). One barrier per D-tile (32 total, was 64);
// stage->barrier distance = full compute+PV, so prefetch drains are free.
// Everything else R18 verbatim (2x2 wave grid 64qx32d, qA[4][8] resident,
// R12-proven sub-slab swizzle, cvt_pk/permlane PV, NSLOT=8).

typedef unsigned short u16;
typedef __bf16 bf16x8 __attribute__((ext_vector_type(8)));
typedef float f32x4 __attribute__((ext_vector_type(4)));
typedef unsigned short u16x4 __attribute__((ext_vector_type(4)));

#define NQ 8192
#define ND 16384
#define NH 256
#define NC 28
#define DCHUNK 2048
#define NDT 32       // 64-row D-tiles per chunk
#define NSLOT 8      // partial slots = 8 D-chunks (one per XCD; wd merged)

__device__ __forceinline__ u16 f2bf(float f) {
  unsigned u = __builtin_bit_cast(unsigned, f);
  u += 0x7fffu + ((u >> 16) & 1u);   // RNE
  return (u16)(u >> 16);
}

__device__ __forceinline__ unsigned cvtpk(float lo, float hi) {
  unsigned r;
  asm("v_cvt_pk_bf16_f32 %0, %1, %2" : "=v"(r) : "v"(lo), "v"(hi));
  return r;  // low16 = bf16(lo), high16 = bf16(hi)  (RNE)
}

// After: x = [x.r0, x.r2, y.r0, y.r2] (by 16-lane row), y = [x.r1, x.r3, y.r1, y.r3]
__device__ __forceinline__ void swap2(unsigned& x, unsigned& y) {
  asm("v_permlane32_swap_b32 %0, %1" : "+v"(x), "+v"(y));  // x.r23 <-> y.r01
  asm("v_permlane16_swap_b32 %0, %1" : "+v"(x), "+v"(y));  // x.r1<->y.r0, x.r3<->y.r2
}

__device__ __forceinline__ void gload16(const void* g, void* l) {
  // async global->LDS, 16B/lane; LDS dest = wave-uniform base + lane*16
  __builtin_amdgcn_global_load_lds(
      (__attribute__((address_space(1))) void*)g,
      (__attribute__((address_space(3))) void*)l, 16, 0, 0);
}

// ---- prep: rows 0..24575 = L2-normalize (feat->qn, exf->kn); then Vt ------
__global__ __launch_bounds__(256) void prep_kernel(
    const float* __restrict__ feat, const float* __restrict__ exf,
    const float* __restrict__ V, u16* __restrict__ qn, u16* __restrict__ kn,
    u16* __restrict__ Vt) {
  if (blockIdx.x < 6144) {
    const int wid = threadIdx.x >> 6, lane = threadIdx.x & 63;
    const int row = blockIdx.x * 4 + wid;
    const float* in = (row < NQ) ? feat + (size_t)row * NH
                                 : exf + (size_t)(row - NQ) * NH;
    u16* out = (row < NQ) ? qn + (size_t)row * NH : kn + (size_t)(row - NQ) * NH;
    float4 v = ((const float4*)in)[lane];
    float ss = v.x * v.x + v.y * v.y + v.z * v.z + v.w * v.w;
#pragma unroll
    for (int m = 1; m <= 32; m <<= 1) ss += __shfl_xor(ss, m, 64);
    const float sc = 1.0f / fmaxf(sqrtf(ss), 1e-12f);  // matches F.normalize eps
    u16x4 o;
    o.x = f2bf(v.x * sc); o.y = f2bf(v.y * sc);
    o.z = f2bf(v.z * sc); o.w = f2bf(v.w * sc);
    *(u16x4*)(out + lane * 4) = o;
  } else {
    const int d = (blockIdx.x - 6144) * 256 + threadIdx.x;  // 16384
#pragma unroll
    for (int c = 0; c < NC; ++c) Vt[(size_t)c * ND + d] = f2bf(V[(size_t)d * NC + c]);
    Vt[(size_t)28 * ND + d] = 0x3F80;  // bf16 1.0 -> echo col 28 == intensity
    Vt[(size_t)29 * ND + d] = 0;
    Vt[(size_t)30 * ND + d] = 0;
    Vt[(size_t)31 * ND + d] = 0;
  }
}

// ---------------- fused main kernel ----------------------------------------
// grid 512: dch = bid&7 (one 2MB K-chunk per XCD, L2-resident), ntile = bid>>3.
// 4 waves, 2x2: wave (wr, wd) owns q-rows [ntile*128+wr*64, +64) x
// d-rows [wd*32, +32) of each 64-row D-tile.
// Q (all H) in registers. LDS 64KB = 2 full-tile bufs [8 k2][64 d][64B].
// Sub-slab swizzle (R12-proven): stored chunk p at row R = logical p^((R>>1)&3).
__global__ __launch_bounds__(256, 2) void fused_kernel(
    const u16* __restrict__ Qn, const u16* __restrict__ Kn,
    const u16* __restrict__ Vt, float* __restrict__ ep) {
  __shared__ alignas(16) char smem[65536];
  const int tid = threadIdx.x;
  const int wid = tid >> 6;
  const int lane = tid & 63;
  const int l16 = lane & 15;
  const int lg = lane >> 4;
  const int wr = wid >> 1;
  const int wd = wid & 1;
  const int dch = blockIdx.x & 7;
  const int ntile = blockIdx.x >> 3;
  const int rowbase = ntile * 128 + wr * 64;

  // ---- Q fragments, 64 rows x all H, in registers (MFMA B-operand) ----
  bf16x8 qA[4][8];
#pragma unroll
  for (int mb = 0; mb < 4; ++mb)
#pragma unroll
    for (int ks = 0; ks < 8; ++ks)
      qA[mb][ks] = *(const bf16x8*)(Qn + (size_t)(rowbase + mb * 16 + l16) * NH +
                                    ks * 32 + lg * 8);

  f32x4 eacc[4][2];
#pragma unroll
  for (int mb = 0; mb < 4; ++mb) {
    eacc[mb][0] = f32x4{0.f, 0.f, 0.f, 0.f};
    eacc[mb][1] = f32x4{0.f, 0.f, 0.f, 0.f};
  }
  f32x4 sacc[4][2];

  const u16* kc = Kn + (size_t)dch * DCHUNK * NH;
  // staging decomposition (per sub-slab r = k2): d = (tid>>6)*16 + ((tid>>2)&15),
  // stored chunk = tid&3, logical chunk = (tid&3) ^ ((tid>>3)&3)
  const int srow = (tid >> 6) * 16 + ((tid >> 2) & 15);
  const u16* kb = kc + (size_t)srow * NH + ((tid & 3) ^ ((tid >> 3) & 3)) * 8;

  // stage one FULL [64d][256k] tile -> buf as 8 sub-slabs [64d][64B]
  auto stage = [&](int buf, const u16* src0) {
#pragma unroll
    for (int r = 0; r < 8; ++r)
      gload16(src0 + r * 32,
              smem + buf * 32768 + r * 4096 + wid * 1024);
  };

  const int rsw = (l16 >> 1) & 3;  // (row>>1)&3 for row = wd*32 + nb*16 + l16

  // compute one staged full tile (buf): 8 k2-steps of 32k each
  auto compute = [&](int buf) {
    const char* kbuf = smem + buf * 32768;
#pragma unroll
    for (int k2 = 0; k2 < 8; ++k2) {
      bf16x8 B[2];
#pragma unroll
      for (int nb = 0; nb < 2; ++nb)
        B[nb] = *(const bf16x8*)(kbuf + k2 * 4096 + (wd * 32 + nb * 16 + l16) * 64 +
                                 ((lg ^ rsw) << 4));
      __builtin_amdgcn_s_setprio(1);
#pragma unroll
      for (int mb = 0; mb < 4; ++mb)
#pragma unroll
        for (int nb = 0; nb < 2; ++nb)
          sacc[mb][nb] = __builtin_amdgcn_mfma_f32_16x16x32_bf16(
              B[nb], qA[mb][k2], sacc[mb][nb], 0, 0, 0);
      __builtin_amdgcn_s_setprio(0);
    }
  };

  // prologue: tile 0 -> buf 0
  stage(0, kb);
  __syncthreads();

  for (int t = 0; t < NDT; ++t) {
    const int cur = t & 1;
    const int dbase = dch * DCHUNK + t * 64 + wd * 32;

#pragma unroll
    for (int mb = 0; mb < 4; ++mb) {
      sacc[mb][0] = f32x4{0.f, 0.f, 0.f, 0.f};
      sacc[mb][1] = f32x4{0.f, 0.f, 0.f, 0.f};
    }

    // prefetch next tile into the other buffer (drains by next barrier,
    // hidden under this tile's full compute + PV)
    if (t < NDT - 1) stage(cur ^ 1, kb + (size_t)(t + 1) * 64 * NH);

    // vB loads: consumed in PV; latency hidden under compute
    bf16x8 vB[2];
#pragma unroll
    for (int cn = 0; cn < 2; ++cn)
      vB[cn] = *(const bf16x8*)(Vt + (size_t)(cn * 16 + l16) * ND + dbase + lg * 8);

    compute(cur);

    // ---- cube (fp32) -> bf16 pack -> permlane transpose -> PV MFMA ----
    // sacc[mb][nb]: q = l16, d = wd*32 + nb*16 + lg*4 + r.  (LDS-free)
#pragma unroll
    for (int mb = 0; mb < 4; ++mb) {
      f32x4 sx = sacc[mb][0];
      f32x4 sy = sacc[mb][1];
      f32x4 cx = sx * sx * sx;
      f32x4 cy = sy * sy * sy;
      unsigned x0 = cvtpk(cx[0], cx[1]);  // d = 4lg+0,1   (nb = 0)
      unsigned x1 = cvtpk(cx[2], cx[3]);  // d = 4lg+2,3
      unsigned y0 = cvtpk(cy[0], cy[1]);  // same, nb = 1
      unsigned y1 = cvtpk(cy[2], cy[3]);
      swap2(x0, y0);  // x0 -> a0 (k 8g+0,1), y0 -> a2 (k 8g+4,5)
      swap2(x1, y1);  // x1 -> a1 (k 8g+2,3), y1 -> a3 (k 8g+6,7)
      const int4 ai = {(int)x0, (int)x1, (int)y0, (int)y1};
      const bf16x8 aA = __builtin_bit_cast(bf16x8, ai);
#pragma unroll
      for (int cn = 0; cn < 2; ++cn)
        eacc[mb][cn] = __builtin_amdgcn_mfma_f32_16x16x32_bf16(
            aA, vB[cn], eacc[mb][cn], 0, 0, 0);
    }

    // single barrier per tile: orders (a) this tile's buf reads before its
    // re-stage at t+2 (issued after this barrier), (b) the prefetch writes
    // (vmcnt-drained here) before compute(cur^1) at t+1.
    __syncthreads();
  }

  // ---- epilogue: merge wd=1 into wd=0 via LDS (bufs dead), slot = dch ----
  float* eml = (float*)smem;  // [2 wr][64 lanes][36 dwords] = 18KB
  if (wd == 1) {
    float* dst = eml + (wr * 64 + lane) * 36;
#pragma unroll
    for (int mb = 0; mb < 4; ++mb)
#pragma unroll
      for (int cn = 0; cn < 2; ++cn)
        *(f32x4*)(dst + (mb * 2 + cn) * 4) = eacc[mb][cn];
  }
  __syncthreads();
  if (wd == 0) {
    const float* src = eml + (wr * 64 + lane) * 36;
#pragma unroll
    for (int mb = 0; mb < 4; ++mb)
#pragma unroll
      for (int cn = 0; cn < 2; ++cn) {
        const f32x4 m = eacc[mb][cn] + *(const f32x4*)(src + (mb * 2 + cn) * 4);
#pragma unroll
        for (int r = 0; r < 4; ++r) {
          const int row = rowbase + mb * 16 + lg * 4 + r;
          ep[((size_t)dch * NQ + row) * 32 + cn * 16 + l16] = m[r];
        }
      }
  }
}

// ---------------- reduce 8 partial slots -> d_out --------------------------
__global__ __launch_bounds__(256) void reduce_kernel(const float* __restrict__ ep,
                                                     float* __restrict__ out) {
  const int g = blockIdx.x * 256 + threadIdx.x;  // 8192*32
  const int q = g >> 5, c = g & 31;
  if (c < NC) {
    float s = 0.f;
#pragma unroll
    for (int k = 0; k < NSLOT; ++k) s += ep[((size_t)k * NQ + q) * 32 + c];
    out[(size_t)q * NC + c] = s;
  } else if (c == NC) {  // ones-column == intensity
    float s = 0.f;
#pragma unroll
    for (int k = 0; k < NSLOT; ++k) s += ep[((size_t)k * NQ + q) * 32 + NC];
    out[(size_t)NQ * NC + q] = s;
  }
}

extern "C" void kernel_launch(void* const* d_in, const int* in_sizes, int n_in,
                              void* d_out, int out_size, void* d_ws, size_t ws_size,
                              hipStream_t stream) {
  const float* feat = (const float*)d_in[0];  // [8192][256]
  const float* exf  = (const float*)d_in[1];  // [16384][256]
  const float* exc  = (const float*)d_in[2];  // [16384][28]
  float* out = (float*)d_out;
  char* ws = (char*)d_ws;
  // ws layout: qn 4MB | kn 8MB | vt 1MB | ep 8MB  (~21MB)
  u16* qn = (u16*)ws;
  u16* kn = (u16*)(ws + 4194304);
  u16* vt = (u16*)(ws + 12582912);
  float* ep = (float*)(ws + 13631488);

  prep_kernel<<<dim3(6208), dim3(256), 0, stream>>>(feat, exf, exc, qn, kn, vt);
  fused_kernel<<<dim3(512), dim3(256), 0, stream>>>(qn, kn, vt, ep);
  reduce_kernel<<<dim3(NQ * 32 / 256), dim3(256), 0, stream>>>(ep, out);
}